// Round 1
// baseline (5585.660 us; speedup 1.0000x reference)
//
#include <hip/hip_runtime.h>
#include <cstdint>

#define HC 168   // H*C
#define CC 42    // C (channels per head)
#define NH 4     // heads
#define NEG 0.2f

__device__ __forceinline__ float lrelu(float v) { return v > 0.f ? v : NEG * v; }
__device__ __forceinline__ float eluf(float v)  { return v > 0.f ? v : __expf(v) - 1.f; }

// Out[N, Ncols] = X[N, Fin] @ W[Fin, Ncols], optional bias+elu epilogue.
// Fin must be a multiple of 42. Tile: 128 rows x 64 cols, thread micro-tile 8x4.
template<bool BIAS_ELU>
__global__ __launch_bounds__(256) void gemm_kernel(
    const float* __restrict__ X, const float* __restrict__ W,
    const float* __restrict__ bias, float* __restrict__ Out,
    int N, int Fin, int Ncols) {
  __shared__ float xs[128][CC];   // 21504 B
  __shared__ float ws[CC][64];    // 10752 B
  const int row0 = blockIdx.x * 128;
  const int col0 = blockIdx.y * 64;
  const int tid = threadIdx.x;
  const int tr = tid >> 4;        // 0..15 row group
  const int tc = tid & 15;        // 0..15 col group
  float acc[8][4];
#pragma unroll
  for (int r = 0; r < 8; ++r)
#pragma unroll
    for (int c = 0; c < 4; ++c) acc[r][c] = 0.f;

  for (int k0 = 0; k0 < Fin; k0 += CC) {
    for (int i = tid; i < 128 * CC; i += 256) {
      int r = i / CC, k = i - r * CC;
      int gr = row0 + r;
      xs[r][k] = (gr < N) ? X[(int64_t)gr * Fin + k0 + k] : 0.f;
    }
    for (int i = tid; i < CC * 64; i += 256) {
      int k = i >> 6, c = i & 63;
      int gc = col0 + c;
      ws[k][c] = (gc < Ncols) ? W[(k0 + k) * Ncols + gc] : 0.f;
    }
    __syncthreads();
#pragma unroll 6
    for (int k = 0; k < CC; ++k) {
      float4 w4 = *(const float4*)&ws[k][tc * 4];
#pragma unroll
      for (int r = 0; r < 8; ++r) {
        float xv = xs[tr * 8 + r][k];
        acc[r][0] += xv * w4.x; acc[r][1] += xv * w4.y;
        acc[r][2] += xv * w4.z; acc[r][3] += xv * w4.w;
      }
    }
    __syncthreads();
  }
#pragma unroll
  for (int r = 0; r < 8; ++r) {
    int gr = row0 + tr * 8 + r;
    if (gr >= N) continue;
#pragma unroll
    for (int c = 0; c < 4; ++c) {
      int gc = col0 + tc * 4 + c;
      if (gc < Ncols) {
        float v = acc[r][c];
        if (BIAS_ELU) v = eluf(v + bias[gc]);
        Out[(int64_t)gr * Ncols + gc] = v;
      }
    }
  }
}

// per (node, head): alpha_src / alpha_dst dot products
__global__ void alpha_kernel(const float* __restrict__ Hf,
                             const float* __restrict__ asrc,
                             const float* __restrict__ adst,
                             float* __restrict__ as_, float* __restrict__ ad_,
                             int N) {
  int i = blockIdx.x * 256 + threadIdx.x;  // over N*NH
  if (i >= N * NH) return;
  int n = i >> 2, h = i & 3;
  const float* hp = Hf + (int64_t)n * HC + h * CC;
  const float* ap = asrc + h * CC;
  const float* bp = adst + h * CC;
  float s = 0.f, d = 0.f;
#pragma unroll 6
  for (int c = 0; c < CC; ++c) { float hv = hp[c]; s += hv * ap[c]; d += hv * bp[c]; }
  as_[i] = s; ad_[i] = d;
}

// self-loop init: acc = h * w_self, denom = w_self
__global__ void selfinit_kernel(const float* __restrict__ Hf,
                                const float* __restrict__ as_,
                                const float* __restrict__ ad_,
                                float* __restrict__ acc, float* __restrict__ denom,
                                int N) {
  int i = blockIdx.x * 256 + threadIdx.x;  // over N*HC
  if (i >= N * HC) return;
  int n = i / HC;
  int j = i - n * HC;
  int h = j / CC;
  float w = __expf(lrelu(as_[n * NH + h] + ad_[n * NH + h]));
  acc[i] = Hf[i] * w;
  if (j == h * CC) denom[n * NH + h] = w;
}

// per edge: exp-weights, accumulate denom (and optionally store weights)
__global__ void edge1_kernel(const int* __restrict__ src, const int* __restrict__ dst,
                             const float* __restrict__ as_, const float* __restrict__ ad_,
                             float* __restrict__ wE, float* __restrict__ denom, int E) {
  int e = blockIdx.x * 256 + threadIdx.x;
  if (e >= E) return;
  int s = src[e], d = dst[e];
  float4 a = *(const float4*)(as_ + s * NH);
  float4 b = *(const float4*)(ad_ + d * NH);
  float w0 = __expf(lrelu(a.x + b.x));
  float w1 = __expf(lrelu(a.y + b.y));
  float w2 = __expf(lrelu(a.z + b.z));
  float w3 = __expf(lrelu(a.w + b.w));
  if (wE) *(float4*)(wE + (int64_t)e * NH) = make_float4(w0, w1, w2, w3);
  atomicAdd(denom + d * NH + 0, w0);
  atomicAdd(denom + d * NH + 1, w1);
  atomicAdd(denom + d * NH + 2, w2);
  atomicAdd(denom + d * NH + 3, w3);
}

// per (edge, channel): acc[dst] += h[src] * w    (stored-weight variant)
__global__ void edge2_kernel(const int* __restrict__ src, const int* __restrict__ dst,
                             const float* __restrict__ Hf, const float* __restrict__ wE,
                             float* __restrict__ acc, int E) {
  int i = blockIdx.x * 256 + threadIdx.x;  // over E*HC (268.8M < 2^31)
  if (i >= E * HC) return;
  int e = i / HC;
  int j = i - e * HC;
  int h = j / CC;
  int s = src[e], d = dst[e];
  float w = wE[(int64_t)e * NH + h];
  atomicAdd(acc + (int64_t)d * HC + j, Hf[(int64_t)s * HC + j] * w);
}

// recompute-weight variant (used if ws too small for wE)
__global__ void edge2_rc_kernel(const int* __restrict__ src, const int* __restrict__ dst,
                                const float* __restrict__ Hf,
                                const float* __restrict__ as_, const float* __restrict__ ad_,
                                float* __restrict__ acc, int E) {
  int i = blockIdx.x * 256 + threadIdx.x;
  if (i >= E * HC) return;
  int e = i / HC;
  int j = i - e * HC;
  int h = j / CC;
  int s = src[e], d = dst[e];
  float w = __expf(lrelu(as_[s * NH + h] + ad_[d * NH + h]));
  atomicAdd(acc + (int64_t)d * HC + j, Hf[(int64_t)s * HC + j] * w);
}

// acc = elu(acc/denom + bias)
__global__ void finalize_kernel(float* __restrict__ acc, const float* __restrict__ denom,
                                const float* __restrict__ bias, int N) {
  int i = blockIdx.x * 256 + threadIdx.x;
  if (i >= N * HC) return;
  int n = i / HC;
  int j = i - n * HC;
  int h = j / CC;
  float v = acc[i] / denom[n * NH + h] + bias[j];
  acc[i] = eluf(v);
}

__global__ void zero_kernel(float* __restrict__ p, int n) {
  int i = blockIdx.x * 256 + threadIdx.x;
  if (i < n) p[i] = 0.f;
}

__global__ void count_kernel(const int* __restrict__ batch, float* __restrict__ counts, int N) {
  int i = blockIdx.x * 256 + threadIdx.x;
  if (i < N) atomicAdd(counts + batch[i], 1.f);
}

__global__ void pool_kernel(const float* __restrict__ x, const int* __restrict__ batch,
                            float* __restrict__ sums, int N) {
  int i = blockIdx.x * 256 + threadIdx.x;  // over N*HC
  if (i >= N * HC) return;
  int n = i / HC;
  int j = i - n * HC;
  atomicAdd(sums + batch[n] * HC + j, x[i]);
}

__global__ void out_kernel(const float* __restrict__ sums, const float* __restrict__ counts,
                           float* __restrict__ out, int G) {
  int i = blockIdx.x * 256 + threadIdx.x;
  if (i >= G * HC) return;
  int g = i / HC;
  out[i] = sums[i] / fmaxf(counts[g], 1.f);
}

static inline int cdiv(int64_t a, int b) { return (int)((a + b - 1) / b); }

extern "C" void kernel_launch(void* const* d_in, const int* in_sizes, int n_in,
                              void* d_out, int out_size, void* d_ws, size_t ws_size,
                              hipStream_t stream) {
  const float* x      = (const float*)d_in[0];
  const int*   eidx   = (const int*)d_in[1];
  const int*   batch  = (const int*)d_in[2];
  const float* lin0_w = (const float*)d_in[3];
  const float* lin0_b = (const float*)d_in[4];
  const float* W[3]  = {(const float*)d_in[5],  (const float*)d_in[9],  (const float*)d_in[13]};
  const float* As[3] = {(const float*)d_in[6],  (const float*)d_in[10], (const float*)d_in[14]};
  const float* Ad[3] = {(const float*)d_in[7],  (const float*)d_in[11], (const float*)d_in[15]};
  const float* Bi[3] = {(const float*)d_in[8],  (const float*)d_in[12], (const float*)d_in[16]};

  const int N = in_sizes[2];
  const int E = in_sizes[1] / 2;
  const int G = out_size / HC;
  const int* src = eidx;
  const int* dst = eidx + E;

  float* p = (float*)d_ws;
  float* bufA  = p; p += (int64_t)N * HC;
  float* bufB  = p; p += (int64_t)N * HC;
  float* as_   = p; p += (int64_t)N * NH;
  float* ad_   = p; p += (int64_t)N * NH;
  float* denom = p; p += (int64_t)N * NH;
  float* sums  = p; p += G * HC;
  float* cnts  = p; p += G;
  // pad to 16B
  p += (4 - ((p - (float*)d_ws) & 3)) & 3;
  float* wE    = p; p += (int64_t)E * NH;
  const size_t needed = (size_t)((char*)p - (char*)d_ws);
  const bool useWE = (needed <= ws_size);

  // ---- lin0 + elu ----
  {
    dim3 grid(cdiv(N, 128), 1);
    gemm_kernel<true><<<grid, 256, 0, stream>>>(x, lin0_w, lin0_b, bufA, N, CC, CC);
  }

  // ---- 3 GAT layers ----
  for (int l = 0; l < 3; ++l) {
    const int Fin = (l == 0) ? CC : HC;
    {
      dim3 grid(cdiv(N, 128), cdiv(HC, 64));
      gemm_kernel<false><<<grid, 256, 0, stream>>>(bufA, W[l], nullptr, bufB, N, Fin, HC);
    }
    alpha_kernel<<<cdiv((int64_t)N * NH, 256), 256, 0, stream>>>(bufB, As[l], Ad[l], as_, ad_, N);
    selfinit_kernel<<<cdiv((int64_t)N * HC, 256), 256, 0, stream>>>(bufB, as_, ad_, bufA, denom, N);
    edge1_kernel<<<cdiv(E, 256), 256, 0, stream>>>(src, dst, as_, ad_,
                                                   useWE ? wE : nullptr, denom, E);
    if (useWE) {
      edge2_kernel<<<cdiv((int64_t)E * HC, 256), 256, 0, stream>>>(src, dst, bufB, wE, bufA, E);
    } else {
      edge2_rc_kernel<<<cdiv((int64_t)E * HC, 256), 256, 0, stream>>>(src, dst, bufB, as_, ad_, bufA, E);
    }
    finalize_kernel<<<cdiv((int64_t)N * HC, 256), 256, 0, stream>>>(bufA, denom, Bi[l], N);
  }

  // ---- mean pool per graph ----
  zero_kernel<<<cdiv(G * HC + G, 256), 256, 0, stream>>>(sums, G * HC + G);  // sums + cnts contiguous
  count_kernel<<<cdiv(N, 256), 256, 0, stream>>>(batch, cnts, N);
  pool_kernel<<<cdiv((int64_t)N * HC, 256), 256, 0, stream>>>(bufA, batch, sums, N);
  out_kernel<<<cdiv(G * HC, 256), 256, 0, stream>>>(sums, cnts, (float*)d_out, G);
}

// Round 2
// 2433.760 us; speedup vs baseline: 2.2951x; 2.2951x over previous
//
#include <hip/hip_runtime.h>
#include <cstdint>

#define HC 168   // H*C
#define CC 42    // C per head
#define NH 4     // heads
#define NEG 0.2f

__device__ __forceinline__ float lrelu(float v) { return v > 0.f ? v : NEG * v; }
__device__ __forceinline__ float eluf(float v)  { return v > 0.f ? v : __expf(v) - 1.f; }

// ---------------- GEMM: Out[N,Ncols] = X[N,Fin] @ W[Fin,Ncols] ----------------
template<bool BIAS_ELU>
__global__ __launch_bounds__(256) void gemm_kernel(
    const float* __restrict__ X, const float* __restrict__ W,
    const float* __restrict__ bias, float* __restrict__ Out,
    int N, int Fin, int Ncols) {
  __shared__ float xs[128][CC];
  __shared__ float ws[CC][64];
  const int row0 = blockIdx.x * 128;
  const int col0 = blockIdx.y * 64;
  const int tid = threadIdx.x;
  const int tr = tid >> 4;
  const int tc = tid & 15;
  float acc[8][4];
#pragma unroll
  for (int r = 0; r < 8; ++r)
#pragma unroll
    for (int c = 0; c < 4; ++c) acc[r][c] = 0.f;

  for (int k0 = 0; k0 < Fin; k0 += CC) {
    for (int i = tid; i < 128 * CC; i += 256) {
      int r = i / CC, k = i - r * CC;
      int gr = row0 + r;
      xs[r][k] = (gr < N) ? X[(int64_t)gr * Fin + k0 + k] : 0.f;
    }
    for (int i = tid; i < CC * 64; i += 256) {
      int k = i >> 6, c = i & 63;
      int gc = col0 + c;
      ws[k][c] = (gc < Ncols) ? W[(k0 + k) * Ncols + gc] : 0.f;
    }
    __syncthreads();
#pragma unroll 6
    for (int k = 0; k < CC; ++k) {
      float4 w4 = *(const float4*)&ws[k][tc * 4];
#pragma unroll
      for (int r = 0; r < 8; ++r) {
        float xv = xs[tr * 8 + r][k];
        acc[r][0] += xv * w4.x; acc[r][1] += xv * w4.y;
        acc[r][2] += xv * w4.z; acc[r][3] += xv * w4.w;
      }
    }
    __syncthreads();
  }
#pragma unroll
  for (int r = 0; r < 8; ++r) {
    int gr = row0 + tr * 8 + r;
    if (gr >= N) continue;
#pragma unroll
    for (int c = 0; c < 4; ++c) {
      int gc = col0 + tc * 4 + c;
      if (gc < Ncols) {
        float v = acc[r][c];
        if (BIAS_ELU) v = eluf(v + bias[gc]);
        Out[(int64_t)gr * Ncols + gc] = v;
      }
    }
  }
}

// ---------------- alpha dot products: [N,H] each ----------------
__global__ void alpha_kernel(const float* __restrict__ Hf,
                             const float* __restrict__ asrc,
                             const float* __restrict__ adst,
                             float* __restrict__ as_, float* __restrict__ ad_,
                             int N) {
  int i = blockIdx.x * 256 + threadIdx.x;
  if (i >= N * NH) return;
  int n = i >> 2, h = i & 3;
  const float* hp = Hf + (int64_t)n * HC + h * CC;
  const float* ap = asrc + h * CC;
  const float* bp = adst + h * CC;
  float s = 0.f, d = 0.f;
#pragma unroll 6
  for (int c = 0; c < CC; ++c) { float hv = hp[c]; s += hv * ap[c]; d += hv * bp[c]; }
  as_[i] = s; ad_[i] = d;
}

// ---------------- counting sort by dst ----------------
__global__ void zero_i_kernel(int* __restrict__ p, int n) {
  int i = blockIdx.x * 256 + threadIdx.x;
  if (i < n) p[i] = 0;
}

__global__ void hist_kernel(const int* __restrict__ dst, int* __restrict__ cnt, int E) {
  int e = blockIdx.x * 256 + threadIdx.x;
  if (e < E) atomicAdd(&cnt[dst[e]], 1);
}

// block-level inclusive scan of 1024 ints -> rp1 (block-local), blksum per block
__global__ __launch_bounds__(256) void scan1_kernel(
    const int* __restrict__ cnt, int* __restrict__ rp1, int* __restrict__ blksum, int N) {
  __shared__ int lds[256];
  int t = threadIdx.x;
  int base = blockIdx.x * 1024 + t * 4;
  int v0 = (base + 0 < N) ? cnt[base + 0] : 0;
  int v1 = (base + 1 < N) ? cnt[base + 1] : 0;
  int v2 = (base + 2 < N) ? cnt[base + 2] : 0;
  int v3 = (base + 3 < N) ? cnt[base + 3] : 0;
  v1 += v0; v2 += v1; v3 += v2;
  lds[t] = v3;
  __syncthreads();
  for (int off = 1; off < 256; off <<= 1) {
    int add = (t >= off) ? lds[t - off] : 0;
    __syncthreads();
    lds[t] += add;
    __syncthreads();
  }
  int excl = lds[t] - v3;
  if (base + 0 < N) rp1[base + 0] = excl + v0;
  if (base + 1 < N) rp1[base + 1] = excl + v1;
  if (base + 2 < N) rp1[base + 2] = excl + v2;
  if (base + 3 < N) rp1[base + 3] = excl + v3;
  if (t == 255) blksum[blockIdx.x] = lds[255];
}

// exclusive scan of block sums (nblk <= 256)
__global__ __launch_bounds__(256) void scan2_kernel(int* __restrict__ blksum, int nblk) {
  __shared__ int lds[256];
  int t = threadIdx.x;
  int v = (t < nblk) ? blksum[t] : 0;
  lds[t] = v;
  __syncthreads();
  for (int off = 1; off < 256; off <<= 1) {
    int add = (t >= off) ? lds[t - off] : 0;
    __syncthreads();
    lds[t] += add;
    __syncthreads();
  }
  if (t < nblk) blksum[t] = lds[t] - v;   // exclusive
}

// finalize: rp1[i] += blkoff; row_ptr[0]=0; cursor[i] = row_ptr[i] (in-place over cnt)
__global__ void scan3_kernel(const int* __restrict__ blksum, int* __restrict__ rp1,
                             int* __restrict__ row_ptr0, int* __restrict__ cnt_cursor, int N) {
  int i = blockIdx.x * 256 + threadIdx.x;
  if (i >= N) return;
  int incl = rp1[i] + blksum[i >> 10];
  rp1[i] = incl;                       // row_ptr[i+1]
  cnt_cursor[i] = incl - cnt_cursor[i];  // row_ptr[i] (exclusive)
  if (i == 0) row_ptr0[0] = 0;
}

__global__ void scatter_kernel(const int* __restrict__ src, const int* __restrict__ dst,
                               int* __restrict__ cursor, int* __restrict__ src_sorted, int E) {
  int e = blockIdx.x * 256 + threadIdx.x;
  if (e >= E) return;
  int pos = atomicAdd(&cursor[dst[e]], 1);
  src_sorted[pos] = src[e];
}

// ---------------- fused GAT aggregation: one wave per dst node ----------------
// lane owns channels {lane, lane+64, lane+128(<168)}; register-accumulated
// weighted sum + denominator; self loop inline; epilogue bias+elu.
__global__ __launch_bounds__(256) void gat_agg_kernel(
    const int* __restrict__ row_ptr, const int* __restrict__ src_sorted,
    const float* __restrict__ Hf, const float* __restrict__ as_,
    const float* __restrict__ ad_, const float* __restrict__ bias,
    float* __restrict__ out, int N) {
  int wid = (blockIdx.x * 256 + threadIdx.x) >> 6;
  int lane = threadIdx.x & 63;
  if (wid >= N) return;
  const int n = wid;
  const int c0 = lane, c1 = lane + 64, c2 = lane + 128;
  const int h0 = c0 / CC;          // 0 or 1
  const int h1 = c1 / CC;          // 1,2,3
  const bool has2 = (c2 < HC);     // lanes 0..39 (head 3)
  const float b0 = ad_[n * NH + h0];
  const float b1 = ad_[n * NH + h1];
  const float b2 = ad_[n * NH + 3];
  float acc0 = 0.f, acc1 = 0.f, acc2 = 0.f;
  float den0 = 0.f, den1 = 0.f, den2 = 0.f;
  const int beg = row_ptr[n], end = row_ptr[n + 1];
  for (int e = beg - 1; e < end; ++e) {
    const int s = (e < beg) ? n : src_sorted[e];   // self loop first
    const float* ap = as_ + s * NH;
    const float w0 = __expf(lrelu(ap[h0] + b0));
    const float w1 = __expf(lrelu(ap[h1] + b1));
    const float w2 = __expf(lrelu(ap[3]  + b2));
    const float* hp = Hf + (int64_t)s * HC;
    acc0 += hp[c0] * w0; den0 += w0;
    acc1 += hp[c1] * w1; den1 += w1;
    if (has2) acc2 += hp[c2] * w2;
    den2 += w2;
  }
  const int64_t o = (int64_t)n * HC;
  out[o + c0] = eluf(acc0 / den0 + bias[c0]);
  out[o + c1] = eluf(acc1 / den1 + bias[c1]);
  if (has2) out[o + c2] = eluf(acc2 / den2 + bias[c2]);
}

// ---------------- mean pool ----------------
__global__ void zero_f_kernel(float* __restrict__ p, int n) {
  int i = blockIdx.x * 256 + threadIdx.x;
  if (i < n) p[i] = 0.f;
}
__global__ void count_kernel(const int* __restrict__ batch, float* __restrict__ counts, int N) {
  int i = blockIdx.x * 256 + threadIdx.x;
  if (i < N) atomicAdd(counts + batch[i], 1.f);
}
__global__ void pool_kernel(const float* __restrict__ x, const int* __restrict__ batch,
                            float* __restrict__ sums, int N) {
  int i = blockIdx.x * 256 + threadIdx.x;
  if (i >= N * HC) return;
  int n = i / HC;
  int j = i - n * HC;
  atomicAdd(sums + batch[n] * HC + j, x[i]);
}
__global__ void out_kernel(const float* __restrict__ sums, const float* __restrict__ counts,
                           float* __restrict__ out, int G) {
  int i = blockIdx.x * 256 + threadIdx.x;
  if (i >= G * HC) return;
  int g = i / HC;
  out[i] = sums[i] / fmaxf(counts[g], 1.f);
}

static inline int cdiv(int64_t a, int b) { return (int)((a + b - 1) / b); }

extern "C" void kernel_launch(void* const* d_in, const int* in_sizes, int n_in,
                              void* d_out, int out_size, void* d_ws, size_t ws_size,
                              hipStream_t stream) {
  const float* x      = (const float*)d_in[0];
  const int*   eidx   = (const int*)d_in[1];
  const int*   batch  = (const int*)d_in[2];
  const float* lin0_w = (const float*)d_in[3];
  const float* lin0_b = (const float*)d_in[4];
  const float* W[3]  = {(const float*)d_in[5],  (const float*)d_in[9],  (const float*)d_in[13]};
  const float* As[3] = {(const float*)d_in[6],  (const float*)d_in[10], (const float*)d_in[14]};
  const float* Ad[3] = {(const float*)d_in[7],  (const float*)d_in[11], (const float*)d_in[15]};
  const float* Bi[3] = {(const float*)d_in[8],  (const float*)d_in[12], (const float*)d_in[16]};

  const int N = in_sizes[2];
  const int E = in_sizes[1] / 2;
  const int G = out_size / HC;
  const int* src = eidx;
  const int* dst = eidx + E;

  // ---- workspace layout ----
  char* p = (char*)d_ws;
  float* bufA = (float*)p; p += (size_t)N * HC * 4;
  float* bufB = (float*)p; p += (size_t)N * HC * 4;
  float* as_  = (float*)p; p += (size_t)N * NH * 4;
  float* ad_  = (float*)p; p += (size_t)N * NH * 4;
  float* sums = (float*)p; p += (size_t)G * HC * 4;
  float* cnts = (float*)p; p += (size_t)G * 4;
  int* row_ptr    = (int*)p; p += (size_t)(N + 1) * 4;   // row_ptr[0..N]
  int* cursor     = (int*)p; p += (size_t)N * 4;         // counts, then cursors
  int* blksum     = (int*)p; p += 256 * 4;
  int* src_sorted = (int*)p; p += (size_t)E * 4;
  (void)ws_size;

  const int nblk = cdiv(N, 1024);

  // ---- lin0 + elu ----
  gemm_kernel<true><<<dim3(cdiv(N, 128), 1), 256, 0, stream>>>(x, lin0_w, lin0_b, bufA, N, CC, CC);

  // ---- build dst-sorted CSR (once; shared by all 3 layers) ----
  zero_i_kernel<<<cdiv(N, 256), 256, 0, stream>>>(cursor, N);
  hist_kernel<<<cdiv(E, 256), 256, 0, stream>>>(dst, cursor, E);
  scan1_kernel<<<nblk, 256, 0, stream>>>(cursor, row_ptr + 1, blksum, N);
  scan2_kernel<<<1, 256, 0, stream>>>(blksum, nblk);
  scan3_kernel<<<cdiv(N, 256), 256, 0, stream>>>(blksum, row_ptr + 1, row_ptr, cursor, N);
  scatter_kernel<<<cdiv(E, 256), 256, 0, stream>>>(src, dst, cursor, src_sorted, E);

  // ---- 3 GAT layers ----
  for (int l = 0; l < 3; ++l) {
    const int Fin = (l == 0) ? CC : HC;
    gemm_kernel<false><<<dim3(cdiv(N, 128), cdiv(HC, 64)), 256, 0, stream>>>(
        bufA, W[l], nullptr, bufB, N, Fin, HC);
    alpha_kernel<<<cdiv((int64_t)N * NH, 256), 256, 0, stream>>>(bufB, As[l], Ad[l], as_, ad_, N);
    gat_agg_kernel<<<cdiv(N, 4), 256, 0, stream>>>(row_ptr, src_sorted, bufB, as_, ad_, Bi[l], bufA, N);
  }

  // ---- mean pool per graph ----
  zero_f_kernel<<<cdiv(G * HC + G, 256), 256, 0, stream>>>(sums, G * HC + G);
  count_kernel<<<cdiv(N, 256), 256, 0, stream>>>(batch, cnts, N);
  pool_kernel<<<cdiv((int64_t)N * HC, 256), 256, 0, stream>>>(bufA, batch, sums, N);
  out_kernel<<<cdiv(G * HC, 256), 256, 0, stream>>>(sums, cnts, (float*)d_out, G);
}

// Round 3
// 1659.993 us; speedup vs baseline: 3.3649x; 1.4661x over previous
//
#include <hip/hip_runtime.h>
#include <cstdint>

#define HC 168   // H*C
#define CC 42    // C per head
#define NH 4     // heads
#define NEG 0.2f

__device__ __forceinline__ float lrelu(float v) { return v > 0.f ? v : NEG * v; }
__device__ __forceinline__ float eluf(float v)  { return v > 0.f ? v : __expf(v) - 1.f; }

// ---------------- GEMM: Out[N,Ncols] = X[N,Fin] @ W[Fin,Ncols] ----------------
template<bool BIAS_ELU>
__global__ __launch_bounds__(256) void gemm_kernel(
    const float* __restrict__ X, const float* __restrict__ W,
    const float* __restrict__ bias, float* __restrict__ Out,
    int N, int Fin, int Ncols) {
  __shared__ float xs[128][CC];
  __shared__ float ws[CC][64];
  const int row0 = blockIdx.x * 128;
  const int col0 = blockIdx.y * 64;
  const int tid = threadIdx.x;
  const int tr = tid >> 4;
  const int tc = tid & 15;
  float acc[8][4];
#pragma unroll
  for (int r = 0; r < 8; ++r)
#pragma unroll
    for (int c = 0; c < 4; ++c) acc[r][c] = 0.f;

  for (int k0 = 0; k0 < Fin; k0 += CC) {
    for (int i = tid; i < 128 * CC; i += 256) {
      int r = i / CC, k = i - r * CC;
      int gr = row0 + r;
      xs[r][k] = (gr < N) ? X[(int64_t)gr * Fin + k0 + k] : 0.f;
    }
    for (int i = tid; i < CC * 64; i += 256) {
      int k = i >> 6, c = i & 63;
      int gc = col0 + c;
      ws[k][c] = (gc < Ncols) ? W[(k0 + k) * Ncols + gc] : 0.f;
    }
    __syncthreads();
#pragma unroll 6
    for (int k = 0; k < CC; ++k) {
      float4 w4 = *(const float4*)&ws[k][tc * 4];
#pragma unroll
      for (int r = 0; r < 8; ++r) {
        float xv = xs[tr * 8 + r][k];
        acc[r][0] += xv * w4.x; acc[r][1] += xv * w4.y;
        acc[r][2] += xv * w4.z; acc[r][3] += xv * w4.w;
      }
    }
    __syncthreads();
  }
#pragma unroll
  for (int r = 0; r < 8; ++r) {
    int gr = row0 + tr * 8 + r;
    if (gr >= N) continue;
#pragma unroll
    for (int c = 0; c < 4; ++c) {
      int gc = col0 + tc * 4 + c;
      if (gc < Ncols) {
        float v = acc[r][c];
        if (BIAS_ELU) v = eluf(v + bias[gc]);
        Out[(int64_t)gr * Ncols + gc] = v;
      }
    }
  }
}

// ---------------- alpha dot products: [N,H] each ----------------
__global__ void alpha_kernel(const float* __restrict__ Hf,
                             const float* __restrict__ asrc,
                             const float* __restrict__ adst,
                             float* __restrict__ as_, float* __restrict__ ad_,
                             int N) {
  int i = blockIdx.x * 256 + threadIdx.x;
  if (i >= N * NH) return;
  int n = i >> 2, h = i & 3;
  const float* hp = Hf + (int64_t)n * HC + h * CC;
  const float* ap = asrc + h * CC;
  const float* bp = adst + h * CC;
  float s = 0.f, d = 0.f;
#pragma unroll 6
  for (int c = 0; c < CC; ++c) { float hv = hp[c]; s += hv * ap[c]; d += hv * bp[c]; }
  as_[i] = s; ad_[i] = d;
}

// ---------------- counting sort by dst ----------------
__global__ void zero_i_kernel(int* __restrict__ p, int n) {
  int i = blockIdx.x * 256 + threadIdx.x;
  if (i < n) p[i] = 0;
}

__global__ void hist_kernel(const int* __restrict__ dst, int* __restrict__ cnt, int E) {
  int e = blockIdx.x * 256 + threadIdx.x;
  if (e < E) atomicAdd(&cnt[dst[e]], 1);
}

__global__ __launch_bounds__(256) void scan1_kernel(
    const int* __restrict__ cnt, int* __restrict__ rp1, int* __restrict__ blksum, int N) {
  __shared__ int lds[256];
  int t = threadIdx.x;
  int base = blockIdx.x * 1024 + t * 4;
  int v0 = (base + 0 < N) ? cnt[base + 0] : 0;
  int v1 = (base + 1 < N) ? cnt[base + 1] : 0;
  int v2 = (base + 2 < N) ? cnt[base + 2] : 0;
  int v3 = (base + 3 < N) ? cnt[base + 3] : 0;
  v1 += v0; v2 += v1; v3 += v2;
  lds[t] = v3;
  __syncthreads();
  for (int off = 1; off < 256; off <<= 1) {
    int add = (t >= off) ? lds[t - off] : 0;
    __syncthreads();
    lds[t] += add;
    __syncthreads();
  }
  int excl = lds[t] - v3;
  if (base + 0 < N) rp1[base + 0] = excl + v0;
  if (base + 1 < N) rp1[base + 1] = excl + v1;
  if (base + 2 < N) rp1[base + 2] = excl + v2;
  if (base + 3 < N) rp1[base + 3] = excl + v3;
  if (t == 255) blksum[blockIdx.x] = lds[255];
}

__global__ __launch_bounds__(256) void scan2_kernel(int* __restrict__ blksum, int nblk) {
  __shared__ int lds[256];
  int t = threadIdx.x;
  int v = (t < nblk) ? blksum[t] : 0;
  lds[t] = v;
  __syncthreads();
  for (int off = 1; off < 256; off <<= 1) {
    int add = (t >= off) ? lds[t - off] : 0;
    __syncthreads();
    lds[t] += add;
    __syncthreads();
  }
  if (t < nblk) blksum[t] = lds[t] - v;   // exclusive
}

__global__ void scan3_kernel(const int* __restrict__ blksum, int* __restrict__ rp1,
                             int* __restrict__ row_ptr0, int* __restrict__ cnt_cursor, int N) {
  int i = blockIdx.x * 256 + threadIdx.x;
  if (i >= N) return;
  int incl = rp1[i] + blksum[i >> 10];
  rp1[i] = incl;                         // row_ptr[i+1]
  cnt_cursor[i] = incl - cnt_cursor[i];  // row_ptr[i] (exclusive)
  if (i == 0) row_ptr0[0] = 0;
}

__global__ void scatter_kernel(const int* __restrict__ src, const int* __restrict__ dst,
                               int* __restrict__ cursor, int* __restrict__ src_sorted, int E) {
  int e = blockIdx.x * 256 + threadIdx.x;
  if (e >= E) return;
  int pos = atomicAdd(&cursor[dst[e]], 1);
  src_sorted[pos] = src[e];
}

// ---------------- fused GAT aggregation: one wave per dst node ----------------
__global__ __launch_bounds__(256) void gat_agg_kernel(
    const int* __restrict__ row_ptr, const int* __restrict__ src_sorted,
    const float* __restrict__ Hf, const float* __restrict__ as_,
    const float* __restrict__ ad_, const float* __restrict__ bias,
    float* __restrict__ out, int N) {
  int wid = (blockIdx.x * 256 + threadIdx.x) >> 6;
  int lane = threadIdx.x & 63;
  if (wid >= N) return;
  const int n = wid;
  const int c0 = lane, c1 = lane + 64, c2 = lane + 128;
  const int h0 = c0 / CC;
  const int h1 = c1 / CC;
  const bool has2 = (c2 < HC);
  const float b0 = ad_[n * NH + h0];
  const float b1 = ad_[n * NH + h1];
  const float b2 = ad_[n * NH + 3];
  float acc0 = 0.f, acc1 = 0.f, acc2 = 0.f;
  float den0 = 0.f, den1 = 0.f, den2 = 0.f;
  const int beg = row_ptr[n], end = row_ptr[n + 1];
  for (int e = beg - 1; e < end; ++e) {
    const int s = (e < beg) ? n : src_sorted[e];   // self loop first
    const float* ap = as_ + s * NH;
    const float w0 = __expf(lrelu(ap[h0] + b0));
    const float w1 = __expf(lrelu(ap[h1] + b1));
    const float w2 = __expf(lrelu(ap[3]  + b2));
    const float* hp = Hf + (int64_t)s * HC;
    acc0 += hp[c0] * w0; den0 += w0;
    acc1 += hp[c1] * w1; den1 += w1;
    if (has2) acc2 += hp[c2] * w2;
    den2 += w2;
  }
  const int64_t o = (int64_t)n * HC;
  out[o + c0] = eluf(acc0 / den0 + bias[c0]);
  out[o + c1] = eluf(acc1 / den1 + bias[c1]);
  if (has2) out[o + c2] = eluf(acc2 / den2 + bias[c2]);
}

// ---------------- mean pool (batch is sorted -> segmented reduce) ----------------
// gstart[g] = first node of graph g; gstart[G] = N; handles empty graphs.
__global__ void gbound_kernel(const int* __restrict__ batch, int* __restrict__ gstart,
                              int N, int G) {
  int i = blockIdx.x * 256 + threadIdx.x;
  if (i > N) return;
  if (i == 0) {
    for (int g = 0; g <= batch[0]; ++g) gstart[g] = 0;
  } else if (i == N) {
    for (int g = batch[N - 1] + 1; g <= G; ++g) gstart[g] = N;
  } else {
    int a = batch[i - 1], b = batch[i];
    for (int g = a + 1; g <= b; ++g) gstart[g] = i;
  }
}

__global__ void zero_f_kernel(float* __restrict__ p, int n) {
  int i = blockIdx.x * 256 + threadIdx.x;
  if (i < n) p[i] = 0.f;
}

// grid (G, PSPLIT); block 192 (threads 0..167 own one channel). Each y-block
// accumulates every-PSPLIT'th row of graph g, then one atomicAdd per channel.
#define PSPLIT 4
__global__ __launch_bounds__(192) void pool2_kernel(
    const float* __restrict__ x, const int* __restrict__ gstart,
    float* __restrict__ sums, int G) {
  int g = blockIdx.x;
  int t = threadIdx.x;
  if (t >= HC) return;
  int beg = gstart[g], end = gstart[g + 1];
  float s = 0.f;
  for (int n = beg + (int)blockIdx.y; n < end; n += PSPLIT)
    s += x[(int64_t)n * HC + t];
  atomicAdd(sums + g * HC + t, s);
}

__global__ void out2_kernel(const float* __restrict__ sums, const int* __restrict__ gstart,
                            float* __restrict__ out, int G) {
  int i = blockIdx.x * 256 + threadIdx.x;
  if (i >= G * HC) return;
  int g = i / HC;
  float cnt = (float)(gstart[g + 1] - gstart[g]);
  out[i] = sums[i] / fmaxf(cnt, 1.f);
}

static inline int cdiv(int64_t a, int b) { return (int)((a + b - 1) / b); }

extern "C" void kernel_launch(void* const* d_in, const int* in_sizes, int n_in,
                              void* d_out, int out_size, void* d_ws, size_t ws_size,
                              hipStream_t stream) {
  const float* x      = (const float*)d_in[0];
  const int*   eidx   = (const int*)d_in[1];
  const int*   batch  = (const int*)d_in[2];
  const float* lin0_w = (const float*)d_in[3];
  const float* lin0_b = (const float*)d_in[4];
  const float* W[3]  = {(const float*)d_in[5],  (const float*)d_in[9],  (const float*)d_in[13]};
  const float* As[3] = {(const float*)d_in[6],  (const float*)d_in[10], (const float*)d_in[14]};
  const float* Ad[3] = {(const float*)d_in[7],  (const float*)d_in[11], (const float*)d_in[15]};
  const float* Bi[3] = {(const float*)d_in[8],  (const float*)d_in[12], (const float*)d_in[16]};

  const int N = in_sizes[2];
  const int E = in_sizes[1] / 2;
  const int G = out_size / HC;
  const int* src = eidx;
  const int* dst = eidx + E;

  // ---- workspace layout ----
  char* p = (char*)d_ws;
  float* bufA = (float*)p; p += (size_t)N * HC * 4;
  float* bufB = (float*)p; p += (size_t)N * HC * 4;
  float* as_  = (float*)p; p += (size_t)N * NH * 4;
  float* ad_  = (float*)p; p += (size_t)N * NH * 4;
  float* sums = (float*)p; p += (size_t)G * HC * 4;
  int* gstart     = (int*)p; p += (size_t)(G + 1) * 4;
  int* row_ptr    = (int*)p; p += (size_t)(N + 1) * 4;
  int* cursor     = (int*)p; p += (size_t)N * 4;
  int* blksum     = (int*)p; p += 256 * 4;
  int* src_sorted = (int*)p; p += (size_t)E * 4;
  (void)ws_size;

  const int nblk = cdiv(N, 1024);

  // ---- lin0 + elu ----
  gemm_kernel<true><<<dim3(cdiv(N, 128), 1), 256, 0, stream>>>(x, lin0_w, lin0_b, bufA, N, CC, CC);

  // ---- build dst-sorted CSR (once; shared by all 3 layers) ----
  zero_i_kernel<<<cdiv(N, 256), 256, 0, stream>>>(cursor, N);
  hist_kernel<<<cdiv(E, 256), 256, 0, stream>>>(dst, cursor, E);
  scan1_kernel<<<nblk, 256, 0, stream>>>(cursor, row_ptr + 1, blksum, N);
  scan2_kernel<<<1, 256, 0, stream>>>(blksum, nblk);
  scan3_kernel<<<cdiv(N, 256), 256, 0, stream>>>(blksum, row_ptr + 1, row_ptr, cursor, N);
  scatter_kernel<<<cdiv(E, 256), 256, 0, stream>>>(src, dst, cursor, src_sorted, E);

  // ---- graph boundaries (batch sorted) ----
  gbound_kernel<<<cdiv(N + 1, 256), 256, 0, stream>>>(batch, gstart, N, G);

  // ---- 3 GAT layers ----
  for (int l = 0; l < 3; ++l) {
    const int Fin = (l == 0) ? CC : HC;
    gemm_kernel<false><<<dim3(cdiv(N, 128), cdiv(HC, 64)), 256, 0, stream>>>(
        bufA, W[l], nullptr, bufB, N, Fin, HC);
    alpha_kernel<<<cdiv((int64_t)N * NH, 256), 256, 0, stream>>>(bufB, As[l], Ad[l], as_, ad_, N);
    gat_agg_kernel<<<cdiv(N, 4), 256, 0, stream>>>(row_ptr, src_sorted, bufB, as_, ad_, Bi[l], bufA, N);
  }

  // ---- mean pool per graph ----
  zero_f_kernel<<<cdiv(G * HC, 256), 256, 0, stream>>>(sums, G * HC);
  pool2_kernel<<<dim3(G, PSPLIT), 192, 0, stream>>>(bufA, gstart, sums, G);
  out2_kernel<<<cdiv(G * HC, 256), 256, 0, stream>>>(sums, gstart, (float*)d_out, G);
}

// Round 4
// 1425.870 us; speedup vs baseline: 3.9174x; 1.1642x over previous
//
#include <hip/hip_runtime.h>
#include <hip/hip_fp16.h>
#include <cstdint>

#define HC 168   // H*C
#define CC 42    // C per head
#define NH 4     // heads
#define NP 84    // half2 pairs per row
#define NEG 0.2f

__device__ __forceinline__ float lrelu(float v) { return fmaxf(v, NEG * v); }
__device__ __forceinline__ float eluf(float v)  { return v > 0.f ? v : __expf(v) - 1.f; }

// ---------------- GEMM: Out[N,Ncols] = X[N,Fin] @ W[Fin,Ncols] ----------------
template<bool BIAS_ELU, typename OutT>
__global__ __launch_bounds__(256) void gemm_kernel(
    const float* __restrict__ X, const float* __restrict__ W,
    const float* __restrict__ bias, OutT* __restrict__ Out,
    int N, int Fin, int Ncols) {
  __shared__ float xs[128][CC];
  __shared__ float ws[CC][64];
  const int row0 = blockIdx.x * 128;
  const int col0 = blockIdx.y * 64;
  const int tid = threadIdx.x;
  const int tr = tid >> 4;
  const int tc = tid & 15;
  float acc[8][4];
#pragma unroll
  for (int r = 0; r < 8; ++r)
#pragma unroll
    for (int c = 0; c < 4; ++c) acc[r][c] = 0.f;

  for (int k0 = 0; k0 < Fin; k0 += CC) {
    for (int i = tid; i < 128 * CC; i += 256) {
      int r = i / CC, k = i - r * CC;
      int gr = row0 + r;
      xs[r][k] = (gr < N) ? X[(int64_t)gr * Fin + k0 + k] : 0.f;
    }
    for (int i = tid; i < CC * 64; i += 256) {
      int k = i >> 6, c = i & 63;
      int gc = col0 + c;
      ws[k][c] = (gc < Ncols) ? W[(k0 + k) * Ncols + gc] : 0.f;
    }
    __syncthreads();
#pragma unroll 6
    for (int k = 0; k < CC; ++k) {
      float4 w4 = *(const float4*)&ws[k][tc * 4];
#pragma unroll
      for (int r = 0; r < 8; ++r) {
        float xv = xs[tr * 8 + r][k];
        acc[r][0] += xv * w4.x; acc[r][1] += xv * w4.y;
        acc[r][2] += xv * w4.z; acc[r][3] += xv * w4.w;
      }
    }
    __syncthreads();
  }
#pragma unroll
  for (int r = 0; r < 8; ++r) {
    int gr = row0 + tr * 8 + r;
    if (gr >= N) continue;
#pragma unroll
    for (int c = 0; c < 4; ++c) {
      int gc = col0 + tc * 4 + c;
      if (gc < Ncols) {
        float v = acc[r][c];
        if (BIAS_ELU) v = eluf(v + bias[gc]);
        Out[(int64_t)gr * Ncols + gc] = (OutT)v;
      }
    }
  }
}

// ---------------- alpha dot products from fp16 h ----------------
__global__ void alpha_kernel(const __half2* __restrict__ H2,
                             const float* __restrict__ asrc,
                             const float* __restrict__ adst,
                             float* __restrict__ as_, float* __restrict__ ad_,
                             int N) {
  int i = blockIdx.x * 256 + threadIdx.x;
  if (i >= N * NH) return;
  int n = i >> 2, h = i & 3;
  const __half2* hp = H2 + (int64_t)n * NP + h * (CC / 2);
  const float* ap = asrc + h * CC;
  const float* bp = adst + h * CC;
  float s = 0.f, d = 0.f;
#pragma unroll 7
  for (int j = 0; j < CC / 2; ++j) {
    float2 f = __half22float2(hp[j]);
    s += f.x * ap[2 * j] + f.y * ap[2 * j + 1];
    d += f.x * bp[2 * j] + f.y * bp[2 * j + 1];
  }
  as_[i] = s; ad_[i] = d;
}

// ---------------- counting sort by dst ----------------
__global__ void zero_i_kernel(int* __restrict__ p, int n) {
  int i = blockIdx.x * 256 + threadIdx.x;
  if (i < n) p[i] = 0;
}

__global__ void hist_kernel(const int* __restrict__ dst, int* __restrict__ cnt, int E) {
  int e = blockIdx.x * 256 + threadIdx.x;
  if (e < E) atomicAdd(&cnt[dst[e]], 1);
}

__global__ __launch_bounds__(256) void scan1_kernel(
    const int* __restrict__ cnt, int* __restrict__ rp1, int* __restrict__ blksum, int N) {
  __shared__ int lds[256];
  int t = threadIdx.x;
  int base = blockIdx.x * 1024 + t * 4;
  int v0 = (base + 0 < N) ? cnt[base + 0] : 0;
  int v1 = (base + 1 < N) ? cnt[base + 1] : 0;
  int v2 = (base + 2 < N) ? cnt[base + 2] : 0;
  int v3 = (base + 3 < N) ? cnt[base + 3] : 0;
  v1 += v0; v2 += v1; v3 += v2;
  lds[t] = v3;
  __syncthreads();
  for (int off = 1; off < 256; off <<= 1) {
    int add = (t >= off) ? lds[t - off] : 0;
    __syncthreads();
    lds[t] += add;
    __syncthreads();
  }
  int excl = lds[t] - v3;
  if (base + 0 < N) rp1[base + 0] = excl + v0;
  if (base + 1 < N) rp1[base + 1] = excl + v1;
  if (base + 2 < N) rp1[base + 2] = excl + v2;
  if (base + 3 < N) rp1[base + 3] = excl + v3;
  if (t == 255) blksum[blockIdx.x] = lds[255];
}

__global__ __launch_bounds__(256) void scan2_kernel(int* __restrict__ blksum, int nblk) {
  __shared__ int lds[256];
  int t = threadIdx.x;
  int v = (t < nblk) ? blksum[t] : 0;
  lds[t] = v;
  __syncthreads();
  for (int off = 1; off < 256; off <<= 1) {
    int add = (t >= off) ? lds[t - off] : 0;
    __syncthreads();
    lds[t] += add;
    __syncthreads();
  }
  if (t < nblk) blksum[t] = lds[t] - v;   // exclusive
}

__global__ void scan3_kernel(const int* __restrict__ blksum, int* __restrict__ rp1,
                             int* __restrict__ row_ptr0, int* __restrict__ cnt_cursor, int N) {
  int i = blockIdx.x * 256 + threadIdx.x;
  if (i >= N) return;
  int incl = rp1[i] + blksum[i >> 10];
  rp1[i] = incl;                         // row_ptr[i+1]
  cnt_cursor[i] = incl - cnt_cursor[i];  // row_ptr[i] (exclusive)
  if (i == 0) row_ptr0[0] = 0;
}

__global__ void scatter_kernel(const int* __restrict__ src, const int* __restrict__ dst,
                               int* __restrict__ cursor, int* __restrict__ src_sorted, int E) {
  int e = blockIdx.x * 256 + threadIdx.x;
  if (e >= E) return;
  int pos = atomicAdd(&cursor[dst[e]], 1);
  src_sorted[pos] = src[e];
}

// ---------------- fused GAT aggregation: one wave per dst node ----------------
// Lane owns half2 pairs {lane, lane+64(<84)}. Pair p covers channels 2p,2p+1;
// head(p) = p/21 (pairs never straddle heads). Self loop peeled; 2x unroll.
__global__ __launch_bounds__(256) void gat_agg_kernel(
    const int* __restrict__ row_ptr, const int* __restrict__ src_sorted,
    const __half2* __restrict__ H2, const float* __restrict__ as_,
    const float* __restrict__ ad_, const float* __restrict__ bias,
    float* __restrict__ out, int N) {
  int wid = (blockIdx.x * 256 + threadIdx.x) >> 6;
  int lane = threadIdx.x & 63;
  if (wid >= N) return;
  const int n = wid;
  const int p0 = lane;
  const int p1 = lane + 64;
  const bool has1 = (p1 < NP);          // lanes 0..19
  const int hA = p0 / 21;               // head of p0 (0..3)
  const float bA = ad_[n * NH + hA];
  const float b3 = ad_[n * NH + 3];
  float aAx = 0.f, aAy = 0.f, aBx = 0.f, aBy = 0.f;
  float denA = 0.f, den3 = 0.f;
  const int beg = row_ptr[n], end = row_ptr[n + 1];

#define GAT_EDGE(s)                                                     \
  {                                                                     \
    const float eA = as_[(s) * NH + hA] + bA;                           \
    const float e3 = as_[(s) * NH + 3] + b3;                            \
    const float wA = __expf(lrelu(eA));                                 \
    const float w3 = __expf(lrelu(e3));                                 \
    const float2 f0 = __half22float2(H2[(int64_t)(s) * NP + p0]);       \
    aAx += f0.x * wA; aAy += f0.y * wA;                                 \
    denA += wA; den3 += w3;                                             \
    if (has1) {                                                         \
      const float2 f1 = __half22float2(H2[(int64_t)(s) * NP + p1]);     \
      aBx += f1.x * w3; aBy += f1.y * w3;                               \
    }                                                                   \
  }

  GAT_EDGE(n);                          // self loop
  int e = beg;
  for (; e + 2 <= end; e += 2) {
    const int s0 = src_sorted[e];
    const int s1 = src_sorted[e + 1];
    GAT_EDGE(s0);
    GAT_EDGE(s1);
  }
  if (e < end) GAT_EDGE(src_sorted[e]);
#undef GAT_EDGE

  float2* o2 = (float2*)(out + (int64_t)n * HC);
  o2[p0] = make_float2(eluf(aAx / denA + bias[2 * p0]),
                       eluf(aAy / denA + bias[2 * p0 + 1]));
  if (has1)
    o2[p1] = make_float2(eluf(aBx / den3 + bias[2 * p1]),
                         eluf(aBy / den3 + bias[2 * p1 + 1]));
}

// ---------------- mean pool (batch sorted -> segmented reduce) ----------------
__global__ void gbound_kernel(const int* __restrict__ batch, int* __restrict__ gstart,
                              int N, int G) {
  int i = blockIdx.x * 256 + threadIdx.x;
  if (i > N) return;
  if (i == 0) {
    for (int g = 0; g <= batch[0]; ++g) gstart[g] = 0;
  } else if (i == N) {
    for (int g = batch[N - 1] + 1; g <= G; ++g) gstart[g] = N;
  } else {
    int a = batch[i - 1], b = batch[i];
    for (int g = a + 1; g <= b; ++g) gstart[g] = i;
  }
}

__global__ void zero_f_kernel(float* __restrict__ p, int n) {
  int i = blockIdx.x * 256 + threadIdx.x;
  if (i < n) p[i] = 0.f;
}

#define PSPLIT 4
__global__ __launch_bounds__(192) void pool2_kernel(
    const float* __restrict__ x, const int* __restrict__ gstart,
    float* __restrict__ sums, int G) {
  int g = blockIdx.x;
  int t = threadIdx.x;
  if (t >= HC) return;
  int beg = gstart[g], end = gstart[g + 1];
  float s = 0.f;
  for (int n = beg + (int)blockIdx.y; n < end; n += PSPLIT)
    s += x[(int64_t)n * HC + t];
  atomicAdd(sums + g * HC + t, s);
}

__global__ void out2_kernel(const float* __restrict__ sums, const int* __restrict__ gstart,
                            float* __restrict__ out, int G) {
  int i = blockIdx.x * 256 + threadIdx.x;
  if (i >= G * HC) return;
  int g = i / HC;
  float cnt = (float)(gstart[g + 1] - gstart[g]);
  out[i] = sums[i] / fmaxf(cnt, 1.f);
}

static inline int cdiv(int64_t a, int b) { return (int)((a + b - 1) / b); }

extern "C" void kernel_launch(void* const* d_in, const int* in_sizes, int n_in,
                              void* d_out, int out_size, void* d_ws, size_t ws_size,
                              hipStream_t stream) {
  const float* x      = (const float*)d_in[0];
  const int*   eidx   = (const int*)d_in[1];
  const int*   batch  = (const int*)d_in[2];
  const float* lin0_w = (const float*)d_in[3];
  const float* lin0_b = (const float*)d_in[4];
  const float* W[3]  = {(const float*)d_in[5],  (const float*)d_in[9],  (const float*)d_in[13]};
  const float* As[3] = {(const float*)d_in[6],  (const float*)d_in[10], (const float*)d_in[14]};
  const float* Ad[3] = {(const float*)d_in[7],  (const float*)d_in[11], (const float*)d_in[15]};
  const float* Bi[3] = {(const float*)d_in[8],  (const float*)d_in[12], (const float*)d_in[16]};

  const int N = in_sizes[2];
  const int E = in_sizes[1] / 2;
  const int G = out_size / HC;
  const int* src = eidx;
  const int* dst = eidx + E;

  // ---- workspace layout ----
  char* p = (char*)d_ws;
  float*   bufA = (float*)p;   p += (size_t)N * HC * 4;   // layer input (fp32)
  __half*  h16  = (__half*)p;  p += (size_t)N * HC * 2;   // layer h (fp16)
  float*   as_  = (float*)p;   p += (size_t)N * NH * 4;
  float*   ad_  = (float*)p;   p += (size_t)N * NH * 4;
  float*   sums = (float*)p;   p += (size_t)G * HC * 4;
  int* gstart     = (int*)p;   p += (size_t)(G + 1) * 4;
  int* row_ptr    = (int*)p;   p += (size_t)(N + 1) * 4;
  int* cursor     = (int*)p;   p += (size_t)N * 4;
  int* blksum     = (int*)p;   p += 256 * 4;
  int* src_sorted = (int*)p;   p += (size_t)E * 4;
  (void)ws_size;

  const __half2* H2 = (const __half2*)h16;
  const int nblk = cdiv(N, 1024);

  // ---- lin0 + elu (fp32 out) ----
  gemm_kernel<true, float><<<dim3(cdiv(N, 128), 1), 256, 0, stream>>>(
      x, lin0_w, lin0_b, bufA, N, CC, CC);

  // ---- build dst-sorted CSR (once) ----
  zero_i_kernel<<<cdiv(N, 256), 256, 0, stream>>>(cursor, N);
  hist_kernel<<<cdiv(E, 256), 256, 0, stream>>>(dst, cursor, E);
  scan1_kernel<<<nblk, 256, 0, stream>>>(cursor, row_ptr + 1, blksum, N);
  scan2_kernel<<<1, 256, 0, stream>>>(blksum, nblk);
  scan3_kernel<<<cdiv(N, 256), 256, 0, stream>>>(blksum, row_ptr + 1, row_ptr, cursor, N);
  scatter_kernel<<<cdiv(E, 256), 256, 0, stream>>>(src, dst, cursor, src_sorted, E);

  // ---- graph boundaries ----
  gbound_kernel<<<cdiv(N + 1, 256), 256, 0, stream>>>(batch, gstart, N, G);

  // ---- 3 GAT layers ----
  for (int l = 0; l < 3; ++l) {
    const int Fin = (l == 0) ? CC : HC;
    gemm_kernel<false, __half><<<dim3(cdiv(N, 128), cdiv(HC, 64)), 256, 0, stream>>>(
        bufA, W[l], nullptr, h16, N, Fin, HC);
    alpha_kernel<<<cdiv((int64_t)N * NH, 256), 256, 0, stream>>>(H2, As[l], Ad[l], as_, ad_, N);
    gat_agg_kernel<<<cdiv(N, 4), 256, 0, stream>>>(row_ptr, src_sorted, H2, as_, ad_, Bi[l], bufA, N);
  }

  // ---- mean pool per graph ----
  zero_f_kernel<<<cdiv(G * HC, 256), 256, 0, stream>>>(sums, G * HC);
  pool2_kernel<<<dim3(G, PSPLIT), 192, 0, stream>>>(bufA, gstart, sums, G);
  out2_kernel<<<cdiv(G * HC, 256), 256, 0, stream>>>(sums, gstart, (float*)d_out, G);
}

// Round 5
// 1204.198 us; speedup vs baseline: 4.6385x; 1.1841x over previous
//
#include <hip/hip_runtime.h>
#include <hip/hip_fp16.h>
#include <cstdint>

#define HC 168   // H*C
#define CC 42    // C per head
#define NH 4     // heads
#define NP 84    // half2 pairs per row
#define NEG 0.2f

__device__ __forceinline__ float lrelu(float v) { return fmaxf(v, NEG * v); }
__device__ __forceinline__ float eluf(float v)  { return v > 0.f ? v : __expf(v) - 1.f; }

__device__ __forceinline__ float sel4(float4 w, int h) {
  float r = w.x;
  r = (h == 1) ? w.y : r;
  r = (h == 2) ? w.z : r;
  r = (h == 3) ? w.w : r;
  return r;
}

// ---------------- GEMM: Out[N,Ncols] = X[N,Fin] @ W[Fin,Ncols] ----------------
template<bool BIAS_ELU, typename OutT>
__global__ __launch_bounds__(256) void gemm_kernel(
    const float* __restrict__ X, const float* __restrict__ W,
    const float* __restrict__ bias, OutT* __restrict__ Out,
    int N, int Fin, int Ncols) {
  __shared__ float xs[128][CC];
  __shared__ float ws[CC][64];
  const int row0 = blockIdx.x * 128;
  const int col0 = blockIdx.y * 64;
  const int tid = threadIdx.x;
  const int tr = tid >> 4;
  const int tc = tid & 15;
  float acc[8][4];
#pragma unroll
  for (int r = 0; r < 8; ++r)
#pragma unroll
    for (int c = 0; c < 4; ++c) acc[r][c] = 0.f;

  for (int k0 = 0; k0 < Fin; k0 += CC) {
    for (int i = tid; i < 128 * CC; i += 256) {
      int r = i / CC, k = i - r * CC;
      int gr = row0 + r;
      xs[r][k] = (gr < N) ? X[(int64_t)gr * Fin + k0 + k] : 0.f;
    }
    for (int i = tid; i < CC * 64; i += 256) {
      int k = i >> 6, c = i & 63;
      int gc = col0 + c;
      ws[k][c] = (gc < Ncols) ? W[(k0 + k) * Ncols + gc] : 0.f;
    }
    __syncthreads();
#pragma unroll 6
    for (int k = 0; k < CC; ++k) {
      float4 w4 = *(const float4*)&ws[k][tc * 4];
#pragma unroll
      for (int r = 0; r < 8; ++r) {
        float xv = xs[tr * 8 + r][k];
        acc[r][0] += xv * w4.x; acc[r][1] += xv * w4.y;
        acc[r][2] += xv * w4.z; acc[r][3] += xv * w4.w;
      }
    }
    __syncthreads();
  }
#pragma unroll
  for (int r = 0; r < 8; ++r) {
    int gr = row0 + tr * 8 + r;
    if (gr >= N) continue;
#pragma unroll
    for (int c = 0; c < 4; ++c) {
      int gc = col0 + tc * 4 + c;
      if (gc < Ncols) {
        float v = acc[r][c];
        if (BIAS_ELU) v = eluf(v + bias[gc]);
        Out[(int64_t)gr * Ncols + gc] = (OutT)v;
      }
    }
  }
}

// ---------------- alpha dot products from fp16 h ----------------
__global__ void alpha_kernel(const __half2* __restrict__ H2,
                             const float* __restrict__ asrc,
                             const float* __restrict__ adst,
                             float* __restrict__ as_, float* __restrict__ ad_,
                             int N) {
  int i = blockIdx.x * 256 + threadIdx.x;
  if (i >= N * NH) return;
  int n = i >> 2, h = i & 3;
  const __half2* hp = H2 + (int64_t)n * NP + h * (CC / 2);
  const float* ap = asrc + h * CC;
  const float* bp = adst + h * CC;
  float s = 0.f, d = 0.f;
#pragma unroll 7
  for (int j = 0; j < CC / 2; ++j) {
    float2 f = __half22float2(hp[j]);
    s += f.x * ap[2 * j] + f.y * ap[2 * j + 1];
    d += f.x * bp[2 * j] + f.y * bp[2 * j + 1];
  }
  as_[i] = s; ad_[i] = d;
}

// ---------------- counting sort by dst ----------------
__global__ void zero_i_kernel(int* __restrict__ p, int n) {
  int i = blockIdx.x * 256 + threadIdx.x;
  if (i < n) p[i] = 0;
}

__global__ void hist_kernel(const int* __restrict__ dst, int* __restrict__ cnt, int E) {
  int e = blockIdx.x * 256 + threadIdx.x;
  if (e < E) atomicAdd(&cnt[dst[e]], 1);
}

__global__ __launch_bounds__(256) void scan1_kernel(
    const int* __restrict__ cnt, int* __restrict__ rp1, int* __restrict__ blksum, int N) {
  __shared__ int lds[256];
  int t = threadIdx.x;
  int base = blockIdx.x * 1024 + t * 4;
  int v0 = (base + 0 < N) ? cnt[base + 0] : 0;
  int v1 = (base + 1 < N) ? cnt[base + 1] : 0;
  int v2 = (base + 2 < N) ? cnt[base + 2] : 0;
  int v3 = (base + 3 < N) ? cnt[base + 3] : 0;
  v1 += v0; v2 += v1; v3 += v2;
  lds[t] = v3;
  __syncthreads();
  for (int off = 1; off < 256; off <<= 1) {
    int add = (t >= off) ? lds[t - off] : 0;
    __syncthreads();
    lds[t] += add;
    __syncthreads();
  }
  int excl = lds[t] - v3;
  if (base + 0 < N) rp1[base + 0] = excl + v0;
  if (base + 1 < N) rp1[base + 1] = excl + v1;
  if (base + 2 < N) rp1[base + 2] = excl + v2;
  if (base + 3 < N) rp1[base + 3] = excl + v3;
  if (t == 255) blksum[blockIdx.x] = lds[255];
}

__global__ __launch_bounds__(256) void scan2_kernel(int* __restrict__ blksum, int nblk) {
  __shared__ int lds[256];
  int t = threadIdx.x;
  int v = (t < nblk) ? blksum[t] : 0;
  lds[t] = v;
  __syncthreads();
  for (int off = 1; off < 256; off <<= 1) {
    int add = (t >= off) ? lds[t - off] : 0;
    __syncthreads();
    lds[t] += add;
    __syncthreads();
  }
  if (t < nblk) blksum[t] = lds[t] - v;   // exclusive
}

__global__ void scan3_kernel(const int* __restrict__ blksum, int* __restrict__ rp1,
                             int* __restrict__ row_ptr0, int* __restrict__ cnt_cursor, int N) {
  int i = blockIdx.x * 256 + threadIdx.x;
  if (i >= N) return;
  int incl = rp1[i] + blksum[i >> 10];
  rp1[i] = incl;                         // row_ptr[i+1]
  cnt_cursor[i] = incl - cnt_cursor[i];  // row_ptr[i] (exclusive)
  if (i == 0) row_ptr0[0] = 0;
}

__global__ void scatter_kernel(const int* __restrict__ src, const int* __restrict__ dst,
                               int* __restrict__ cursor, int* __restrict__ src_sorted, int E) {
  int e = blockIdx.x * 256 + threadIdx.x;
  if (e >= E) return;
  int pos = atomicAdd(&cursor[dst[e]], 1);
  src_sorted[pos] = src[e];
}

// ---------------- fused GAT aggregation: one wave per dst node ----------------
// Cooperative: per 64-edge chunk, lane j loads src idx + as4[idx], computes all
// 4 head weights, stashes {idx, w4} in wave-private LDS. Inner loop: uniform
// LDS broadcast reads + ONE 8B gather per edge (lane l<42 owns pairs 2l,2l+1 =
// channels 4l..4l+3), 4x unrolled for 4 gathers in flight.
__global__ __launch_bounds__(256) void gat_agg_kernel(
    const int* __restrict__ row_ptr, const int* __restrict__ src_sorted,
    const __half2* __restrict__ H2, const float4* __restrict__ as4,
    const float4* __restrict__ ad4_, const float* __restrict__ bias,
    float* __restrict__ out, int N) {
  __shared__ int    lidx[4][64];
  __shared__ float4 lw[4][64];
  const int wv = threadIdx.x >> 6;
  const int lane = threadIdx.x & 63;
  const int wid = (blockIdx.x * 256 + threadIdx.x) >> 6;
  if (wid >= N) return;               // no barriers in kernel; LDS is wave-private
  const int n = wid;
  const bool act = (lane < 42);
  const int p0 = 2 * lane;
  const int hX = p0 / 21;             // head of pair p0   (garbage >3 for lane>=42, unused)
  const int hY = (p0 + 1) / 21;       // head of pair p0+1
  const float4 adn = ad4_[n];
  float ax0 = 0.f, ay0 = 0.f, ax1 = 0.f, ay1 = 0.f, denA = 0.f, denB = 0.f;

#define GAT_ACC(s_, wX_, wY_)                                               \
  {                                                                         \
    denA += wX_; denB += wY_;                                               \
    if (act) {                                                              \
      float2 raw = *(const float2*)(H2 + (int64_t)(s_) * NP + p0);          \
      __half2 u0 = *(__half2*)&raw.x, u1 = *(__half2*)&raw.y;               \
      float2 f0 = __half22float2(u0), f1 = __half22float2(u1);              \
      ax0 += f0.x * wX_; ay0 += f0.y * wX_;                                 \
      ax1 += f1.x * wY_; ay1 += f1.y * wY_;                                 \
    }                                                                       \
  }

  // self loop
  {
    const float4 a4 = as4[n];
    float4 w4 = make_float4(__expf(lrelu(a4.x + adn.x)), __expf(lrelu(a4.y + adn.y)),
                            __expf(lrelu(a4.z + adn.z)), __expf(lrelu(a4.w + adn.w)));
    float wX = sel4(w4, hX), wY = sel4(w4, hY);
    GAT_ACC(n, wX, wY);
  }

  const int beg = row_ptr[n], end = row_ptr[n + 1];
  for (int base = beg; base < end; base += 64) {
    const int m = min(64, end - base);
    int idx = (lane < m) ? src_sorted[base + lane] : n;
    float4 a4 = as4[idx];
    float4 w4 = make_float4(__expf(lrelu(a4.x + adn.x)), __expf(lrelu(a4.y + adn.y)),
                            __expf(lrelu(a4.z + adn.z)), __expf(lrelu(a4.w + adn.w)));
    lidx[wv][lane] = idx;
    lw[wv][lane] = w4;

#define GAT_EDGE(jj)                                                        \
    {                                                                       \
      int s = lidx[wv][jj];                                                 \
      float4 ww = lw[wv][jj];                                               \
      float wX = sel4(ww, hX), wY = sel4(ww, hY);                           \
      GAT_ACC(s, wX, wY);                                                   \
    }

    int j = 0;
    for (; j + 4 <= m; j += 4) {
      GAT_EDGE(j) GAT_EDGE(j + 1) GAT_EDGE(j + 2) GAT_EDGE(j + 3)
    }
    for (; j < m; ++j) GAT_EDGE(j)
#undef GAT_EDGE
  }
#undef GAT_ACC

  if (act) {
    float4 b4 = *(const float4*)(bias + 4 * lane);
    float4 o;
    o.x = eluf(ax0 / denA + b4.x);
    o.y = eluf(ay0 / denA + b4.y);
    o.z = eluf(ax1 / denB + b4.z);
    o.w = eluf(ay1 / denB + b4.w);
    *(float4*)(out + (int64_t)n * HC + 4 * lane) = o;
  }
}

// ---------------- mean pool (batch sorted -> segmented reduce) ----------------
__global__ void gbound_kernel(const int* __restrict__ batch, int* __restrict__ gstart,
                              int N, int G) {
  int i = blockIdx.x * 256 + threadIdx.x;
  if (i > N) return;
  if (i == 0) {
    for (int g = 0; g <= batch[0]; ++g) gstart[g] = 0;
  } else if (i == N) {
    for (int g = batch[N - 1] + 1; g <= G; ++g) gstart[g] = N;
  } else {
    int a = batch[i - 1], b = batch[i];
    for (int g = a + 1; g <= b; ++g) gstart[g] = i;
  }
}

__global__ void zero_f_kernel(float* __restrict__ p, int n) {
  int i = blockIdx.x * 256 + threadIdx.x;
  if (i < n) p[i] = 0.f;
}

#define PSPLIT 4
__global__ __launch_bounds__(192) void pool2_kernel(
    const float* __restrict__ x, const int* __restrict__ gstart,
    float* __restrict__ sums, int G) {
  int g = blockIdx.x;
  int t = threadIdx.x;
  if (t >= HC) return;
  int beg = gstart[g], end = gstart[g + 1];
  float s = 0.f;
  for (int n = beg + (int)blockIdx.y; n < end; n += PSPLIT)
    s += x[(int64_t)n * HC + t];
  atomicAdd(sums + g * HC + t, s);
}

__global__ void out2_kernel(const float* __restrict__ sums, const int* __restrict__ gstart,
                            float* __restrict__ out, int G) {
  int i = blockIdx.x * 256 + threadIdx.x;
  if (i >= G * HC) return;
  int g = i / HC;
  float cnt = (float)(gstart[g + 1] - gstart[g]);
  out[i] = sums[i] / fmaxf(cnt, 1.f);
}

static inline int cdiv(int64_t a, int b) { return (int)((a + b - 1) / b); }

extern "C" void kernel_launch(void* const* d_in, const int* in_sizes, int n_in,
                              void* d_out, int out_size, void* d_ws, size_t ws_size,
                              hipStream_t stream) {
  const float* x      = (const float*)d_in[0];
  const int*   eidx   = (const int*)d_in[1];
  const int*   batch  = (const int*)d_in[2];
  const float* lin0_w = (const float*)d_in[3];
  const float* lin0_b = (const float*)d_in[4];
  const float* W[3]  = {(const float*)d_in[5],  (const float*)d_in[9],  (const float*)d_in[13]};
  const float* As[3] = {(const float*)d_in[6],  (const float*)d_in[10], (const float*)d_in[14]};
  const float* Ad[3] = {(const float*)d_in[7],  (const float*)d_in[11], (const float*)d_in[15]};
  const float* Bi[3] = {(const float*)d_in[8],  (const float*)d_in[12], (const float*)d_in[16]};

  const int N = in_sizes[2];
  const int E = in_sizes[1] / 2;
  const int G = out_size / HC;
  const int* src = eidx;
  const int* dst = eidx + E;

  // ---- workspace layout ----
  char* p = (char*)d_ws;
  float*   bufA = (float*)p;   p += (size_t)N * HC * 4;   // layer input (fp32)
  __half*  h16  = (__half*)p;  p += (size_t)N * HC * 2;   // layer h (fp16)
  float*   as_  = (float*)p;   p += (size_t)N * NH * 4;
  float*   ad_  = (float*)p;   p += (size_t)N * NH * 4;
  float*   sums = (float*)p;   p += (size_t)G * HC * 4;
  int* gstart     = (int*)p;   p += (size_t)(G + 1) * 4;
  int* row_ptr    = (int*)p;   p += (size_t)(N + 1) * 4;
  int* cursor     = (int*)p;   p += (size_t)N * 4;
  int* blksum     = (int*)p;   p += 256 * 4;
  int* src_sorted = (int*)p;   p += (size_t)E * 4;
  (void)ws_size;

  const __half2* H2 = (const __half2*)h16;
  const int nblk = cdiv(N, 1024);

  // ---- lin0 + elu (fp32 out) ----
  gemm_kernel<true, float><<<dim3(cdiv(N, 128), 1), 256, 0, stream>>>(
      x, lin0_w, lin0_b, bufA, N, CC, CC);

  // ---- build dst-sorted CSR (once) ----
  zero_i_kernel<<<cdiv(N, 256), 256, 0, stream>>>(cursor, N);
  hist_kernel<<<cdiv(E, 256), 256, 0, stream>>>(dst, cursor, E);
  scan1_kernel<<<nblk, 256, 0, stream>>>(cursor, row_ptr + 1, blksum, N);
  scan2_kernel<<<1, 256, 0, stream>>>(blksum, nblk);
  scan3_kernel<<<cdiv(N, 256), 256, 0, stream>>>(blksum, row_ptr + 1, row_ptr, cursor, N);
  scatter_kernel<<<cdiv(E, 256), 256, 0, stream>>>(src, dst, cursor, src_sorted, E);

  // ---- graph boundaries ----
  gbound_kernel<<<cdiv(N + 1, 256), 256, 0, stream>>>(batch, gstart, N, G);

  // ---- 3 GAT layers ----
  for (int l = 0; l < 3; ++l) {
    const int Fin = (l == 0) ? CC : HC;
    gemm_kernel<false, __half><<<dim3(cdiv(N, 128), cdiv(HC, 64)), 256, 0, stream>>>(
        bufA, W[l], nullptr, h16, N, Fin, HC);
    alpha_kernel<<<cdiv((int64_t)N * NH, 256), 256, 0, stream>>>(H2, As[l], Ad[l], as_, ad_, N);
    gat_agg_kernel<<<cdiv(N, 4), 256, 0, stream>>>(
        row_ptr, src_sorted, H2, (const float4*)as_, (const float4*)ad_, Bi[l], bufA, N);
  }

  // ---- mean pool per graph ----
  zero_f_kernel<<<cdiv(G * HC, 256), 256, 0, stream>>>(sums, G * HC);
  pool2_kernel<<<dim3(G, PSPLIT), 192, 0, stream>>>(bufA, gstart, sums, G);
  out2_kernel<<<cdiv(G * HC, 256), 256, 0, stream>>>(sums, gstart, (float*)d_out, G);
}

// Round 6
// 886.002 us; speedup vs baseline: 6.3043x; 1.3591x over previous
//
#include <hip/hip_runtime.h>
#include <hip/hip_fp16.h>
#include <cstdint>

#define HC 168   // H*C
#define CC 42    // C per head
#define NH 4     // heads
#define NP 84    // half2 pairs per h16 row
#define AP 192   // act row pitch (halves), zero-padded K for KCN=6
#define A0P 64   // act0 row pitch (halves), zero-padded K for KCN=2
#define NEG 0.2f

typedef _Float16 f16;
typedef __attribute__((ext_vector_type(8))) _Float16 f16x8;
typedef __attribute__((ext_vector_type(4))) float f32x4;

__device__ __forceinline__ float lrelu(float v) { return fmaxf(v, NEG * v); }
__device__ __forceinline__ float eluf(float v)  { return v > 0.f ? v : __expf(v) - 1.f; }

__device__ __forceinline__ float sel4(float4 w, int h) {
  float r = w.x;
  r = (h == 1) ? w.y : r;
  r = (h == 2) ? w.z : r;
  r = (h == 3) ? w.w : r;
  return r;
}

// ---------------- lin0: fp32 vector GEMM, fp16 padded output ----------------
__global__ __launch_bounds__(256) void gemm0_kernel(
    const float* __restrict__ X, const float* __restrict__ W,
    const float* __restrict__ bias, f16* __restrict__ Out,
    int N, int Fin, int Ncols, int pitch) {
  __shared__ float xs[128][CC];
  __shared__ float ws[CC][64];
  const int row0 = blockIdx.x * 128;
  const int col0 = blockIdx.y * 64;
  const int tid = threadIdx.x;
  const int tr = tid >> 4;
  const int tc = tid & 15;
  float acc[8][4];
#pragma unroll
  for (int r = 0; r < 8; ++r)
#pragma unroll
    for (int c = 0; c < 4; ++c) acc[r][c] = 0.f;

  for (int k0 = 0; k0 < Fin; k0 += CC) {
    for (int i = tid; i < 128 * CC; i += 256) {
      int r = i / CC, k = i - r * CC;
      int gr = row0 + r;
      xs[r][k] = (gr < N) ? X[(int64_t)gr * Fin + k0 + k] : 0.f;
    }
    for (int i = tid; i < CC * 64; i += 256) {
      int k = i >> 6, c = i & 63;
      int gc = col0 + c;
      ws[k][c] = (gc < Ncols) ? W[(k0 + k) * Ncols + gc] : 0.f;
    }
    __syncthreads();
#pragma unroll 6
    for (int k = 0; k < CC; ++k) {
      float4 w4 = *(const float4*)&ws[k][tc * 4];
#pragma unroll
      for (int r = 0; r < 8; ++r) {
        float xv = xs[tr * 8 + r][k];
        acc[r][0] += xv * w4.x; acc[r][1] += xv * w4.y;
        acc[r][2] += xv * w4.z; acc[r][3] += xv * w4.w;
      }
    }
    __syncthreads();
  }
#pragma unroll
  for (int r = 0; r < 8; ++r) {
    int gr = row0 + tr * 8 + r;
    if (gr >= N) continue;
#pragma unroll
    for (int c = 0; c < 4; ++c) {
      int gc = col0 + tc * 4 + c;
      if (gc < pitch) {
        f16 o = (f16)0.f;
        if (gc < Ncols) o = (f16)eluf(acc[r][c] + bias[gc]);
        Out[(int64_t)gr * pitch + gc] = o;
      }
    }
  }
}

// ---------------- W -> fragment-layout fp16 table ----------------
// Wf[((ct*KCN + kc)*64 + lane)*8 + j] = W[kc*32 + (lane>>4)*8 + j][ct*16 + (lane&15)]
__global__ void wconv_kernel(const float* __restrict__ W, f16* __restrict__ Wf,
                             int Fin, int KCN) {
  int i = blockIdx.x * 256 + threadIdx.x;
  int tot = 11 * KCN * 64;
  if (i >= tot) return;
  int lane = i & 63;
  int t = i >> 6;
  int kc = t % KCN;
  int ct = t / KCN;
  int r = lane & 15, g = lane >> 4;
  int col = ct * 16 + r;
  f16 vals[8];
#pragma unroll
  for (int j = 0; j < 8; ++j) {
    int k = kc * 32 + g * 8 + j;
    float v = (k < Fin && col < HC) ? W[k * HC + col] : 0.f;
    vals[j] = (f16)v;
  }
  *(f16x8*)(Wf + (size_t)i * 8) = *(f16x8*)vals;
}

// ---------------- MFMA GEMM: h16[N,168] = act[N,KCN*32] @ Wf ----------------
// One wave per 16-row tile, no LDS. A/B use identical per-lane k maps, so the
// result is invariant to the exact k permutation; D: col=lane&15, row=(lane>>4)*4+v.
template<int KCN>
__global__ __launch_bounds__(256) void mfma_gemm_kernel(
    const f16* __restrict__ A, const f16* __restrict__ Wf,
    f16* __restrict__ Out, int N) {
  const int lane = threadIdx.x & 63;
  const int wid = (blockIdx.x * 256 + threadIdx.x) >> 6;
  const int row0 = wid * 16;
  if (row0 >= N) return;
  const int r = lane & 15, g = lane >> 4;
  f16x8 a[KCN];
  const f16* ap = A + (int64_t)(row0 + r) * (KCN * 32) + g * 8;
#pragma unroll
  for (int kc = 0; kc < KCN; ++kc)
    a[kc] = *(const f16x8*)(ap + kc * 32);
  f16* op = Out + (int64_t)row0 * HC;
#pragma unroll
  for (int ct = 0; ct < 11; ++ct) {
    f32x4 acc = {0.f, 0.f, 0.f, 0.f};
#pragma unroll
    for (int kc = 0; kc < KCN; ++kc) {
      f16x8 b = *(const f16x8*)(Wf + (((size_t)ct * KCN + kc) * 64 + lane) * 8);
      acc = __builtin_amdgcn_mfma_f32_16x16x32_f16(a[kc], b, acc, 0, 0, 0);
    }
    const int col = ct * 16 + r;
    if (col < HC) {
#pragma unroll
      for (int v = 0; v < 4; ++v)
        op[(int64_t)(g * 4 + v) * HC + col] = (f16)acc[v];
    }
  }
}

// ---------------- alpha dot products from fp16 h ----------------
__global__ void alpha_kernel(const __half2* __restrict__ H2,
                             const float* __restrict__ asrc,
                             const float* __restrict__ adst,
                             float* __restrict__ as_, float* __restrict__ ad_,
                             int N) {
  int i = blockIdx.x * 256 + threadIdx.x;
  if (i >= N * NH) return;
  int n = i >> 2, h = i & 3;
  const __half2* hp = H2 + (int64_t)n * NP + h * (CC / 2);
  const float* ap = asrc + h * CC;
  const float* bp = adst + h * CC;
  float s = 0.f, d = 0.f;
#pragma unroll 7
  for (int j = 0; j < CC / 2; ++j) {
    float2 f = __half22float2(hp[j]);
    s += f.x * ap[2 * j] + f.y * ap[2 * j + 1];
    d += f.x * bp[2 * j] + f.y * bp[2 * j + 1];
  }
  as_[i] = s; ad_[i] = d;
}

// ---------------- counting sort by dst ----------------
__global__ void zero_i_kernel(int* __restrict__ p, int n) {
  int i = blockIdx.x * 256 + threadIdx.x;
  if (i < n) p[i] = 0;
}

__global__ void hist_kernel(const int* __restrict__ dst, int* __restrict__ cnt, int E) {
  int e = blockIdx.x * 256 + threadIdx.x;
  if (e < E) atomicAdd(&cnt[dst[e]], 1);
}

__global__ __launch_bounds__(256) void scan1_kernel(
    const int* __restrict__ cnt, int* __restrict__ rp1, int* __restrict__ blksum, int N) {
  __shared__ int lds[256];
  int t = threadIdx.x;
  int base = blockIdx.x * 1024 + t * 4;
  int v0 = (base + 0 < N) ? cnt[base + 0] : 0;
  int v1 = (base + 1 < N) ? cnt[base + 1] : 0;
  int v2 = (base + 2 < N) ? cnt[base + 2] : 0;
  int v3 = (base + 3 < N) ? cnt[base + 3] : 0;
  v1 += v0; v2 += v1; v3 += v2;
  lds[t] = v3;
  __syncthreads();
  for (int off = 1; off < 256; off <<= 1) {
    int add = (t >= off) ? lds[t - off] : 0;
    __syncthreads();
    lds[t] += add;
    __syncthreads();
  }
  int excl = lds[t] - v3;
  if (base + 0 < N) rp1[base + 0] = excl + v0;
  if (base + 1 < N) rp1[base + 1] = excl + v1;
  if (base + 2 < N) rp1[base + 2] = excl + v2;
  if (base + 3 < N) rp1[base + 3] = excl + v3;
  if (t == 255) blksum[blockIdx.x] = lds[255];
}

__global__ __launch_bounds__(256) void scan2_kernel(int* __restrict__ blksum, int nblk) {
  __shared__ int lds[256];
  int t = threadIdx.x;
  int v = (t < nblk) ? blksum[t] : 0;
  lds[t] = v;
  __syncthreads();
  for (int off = 1; off < 256; off <<= 1) {
    int add = (t >= off) ? lds[t - off] : 0;
    __syncthreads();
    lds[t] += add;
    __syncthreads();
  }
  if (t < nblk) blksum[t] = lds[t] - v;   // exclusive
}

__global__ void scan3_kernel(const int* __restrict__ blksum, int* __restrict__ rp1,
                             int* __restrict__ row_ptr0, int* __restrict__ cnt_cursor, int N) {
  int i = blockIdx.x * 256 + threadIdx.x;
  if (i >= N) return;
  int incl = rp1[i] + blksum[i >> 10];
  rp1[i] = incl;                         // row_ptr[i+1]
  cnt_cursor[i] = incl - cnt_cursor[i];  // row_ptr[i] (exclusive)
  if (i == 0) row_ptr0[0] = 0;
}

__global__ void scatter_kernel(const int* __restrict__ src, const int* __restrict__ dst,
                               int* __restrict__ cursor, int* __restrict__ src_sorted, int E) {
  int e = blockIdx.x * 256 + threadIdx.x;
  if (e >= E) return;
  int pos = atomicAdd(&cursor[dst[e]], 1);
  src_sorted[pos] = src[e];
}

// ---------------- fused GAT aggregation: one wave per dst node ----------------
// Output: fp16 act rows with pitch AP=192, pad halves 168..191 zeroed.
__global__ __launch_bounds__(256) void gat_agg_kernel(
    const int* __restrict__ row_ptr, const int* __restrict__ src_sorted,
    const __half2* __restrict__ H2, const float4* __restrict__ as4,
    const float4* __restrict__ ad4_, const float* __restrict__ bias,
    __half* __restrict__ out, int N) {
  __shared__ int    lidx[4][64];
  __shared__ float4 lw[4][64];
  const int wv = threadIdx.x >> 6;
  const int lane = threadIdx.x & 63;
  const int wid = (blockIdx.x * 256 + threadIdx.x) >> 6;
  if (wid >= N) return;               // no barriers; LDS is wave-private
  const int n = wid;
  const bool act = (lane < 42);
  const int p0 = 2 * lane;
  const int hX = p0 / 21;
  const int hY = (p0 + 1) / 21;
  const float4 adn = ad4_[n];
  float ax0 = 0.f, ay0 = 0.f, ax1 = 0.f, ay1 = 0.f, denA = 0.f, denB = 0.f;

#define GAT_ACC(s_, wX_, wY_)                                               \
  {                                                                         \
    denA += wX_; denB += wY_;                                               \
    if (act) {                                                              \
      float2 raw = *(const float2*)(H2 + (int64_t)(s_) * NP + p0);          \
      __half2 u0 = *(__half2*)&raw.x, u1 = *(__half2*)&raw.y;               \
      float2 f0 = __half22float2(u0), f1 = __half22float2(u1);              \
      ax0 += f0.x * wX_; ay0 += f0.y * wX_;                                 \
      ax1 += f1.x * wY_; ay1 += f1.y * wY_;                                 \
    }                                                                       \
  }

  // self loop
  {
    const float4 a4 = as4[n];
    float4 w4 = make_float4(__expf(lrelu(a4.x + adn.x)), __expf(lrelu(a4.y + adn.y)),
                            __expf(lrelu(a4.z + adn.z)), __expf(lrelu(a4.w + adn.w)));
    float wX = sel4(w4, hX), wY = sel4(w4, hY);
    GAT_ACC(n, wX, wY);
  }

  const int beg = row_ptr[n], end = row_ptr[n + 1];
  for (int base = beg; base < end; base += 64) {
    const int m = min(64, end - base);
    int idx = (lane < m) ? src_sorted[base + lane] : n;
    float4 a4 = as4[idx];
    float4 w4 = make_float4(__expf(lrelu(a4.x + adn.x)), __expf(lrelu(a4.y + adn.y)),
                            __expf(lrelu(a4.z + adn.z)), __expf(lrelu(a4.w + adn.w)));
    lidx[wv][lane] = idx;
    lw[wv][lane] = w4;

#define GAT_EDGE(jj)                                                        \
    {                                                                       \
      int s = lidx[wv][jj];                                                 \
      float4 ww = lw[wv][jj];                                               \
      float wX = sel4(ww, hX), wY = sel4(ww, hY);                           \
      GAT_ACC(s, wX, wY);                                                   \
    }

    int j = 0;
    for (; j + 4 <= m; j += 4) {
      GAT_EDGE(j) GAT_EDGE(j + 1) GAT_EDGE(j + 2) GAT_EDGE(j + 3)
    }
    for (; j < m; ++j) GAT_EDGE(j)
#undef GAT_EDGE
  }
#undef GAT_ACC

  if (act) {
    float4 b4 = *(const float4*)(bias + 4 * lane);
    union { __half h[4]; uint2 u; } ob;
    ob.h[0] = __float2half(eluf(ax0 / denA + b4.x));
    ob.h[1] = __float2half(eluf(ay0 / denA + b4.y));
    ob.h[2] = __float2half(eluf(ax1 / denB + b4.z));
    ob.h[3] = __float2half(eluf(ay1 / denB + b4.w));
    *(uint2*)(out + (int64_t)n * AP + 4 * lane) = ob.u;
  } else if (lane < 48) {             // zero the K-pad halves 168..191
    *(uint2*)(out + (int64_t)n * AP + 4 * lane) = make_uint2(0u, 0u);
  }
}

// ---------------- mean pool (batch sorted -> segmented reduce) ----------------
__global__ void gbound_kernel(const int* __restrict__ batch, int* __restrict__ gstart,
                              int N, int G) {
  int i = blockIdx.x * 256 + threadIdx.x;
  if (i > N) return;
  if (i == 0) {
    for (int g = 0; g <= batch[0]; ++g) gstart[g] = 0;
  } else if (i == N) {
    for (int g = batch[N - 1] + 1; g <= G; ++g) gstart[g] = N;
  } else {
    int a = batch[i - 1], b = batch[i];
    for (int g = a + 1; g <= b; ++g) gstart[g] = i;
  }
}

__global__ void zero_f_kernel(float* __restrict__ p, int n) {
  int i = blockIdx.x * 256 + threadIdx.x;
  if (i < n) p[i] = 0.f;
}

#define PSPLIT 4
__global__ __launch_bounds__(192) void pool2_kernel(
    const __half* __restrict__ x, const int* __restrict__ gstart,
    float* __restrict__ sums, int G) {
  int g = blockIdx.x;
  int t = threadIdx.x;
  if (t >= HC) return;
  int beg = gstart[g], end = gstart[g + 1];
  float s = 0.f;
  for (int n = beg + (int)blockIdx.y; n < end; n += PSPLIT)
    s += __half2float(x[(int64_t)n * AP + t]);
  atomicAdd(sums + g * HC + t, s);
}

__global__ void out2_kernel(const float* __restrict__ sums, const int* __restrict__ gstart,
                            float* __restrict__ out, int G) {
  int i = blockIdx.x * 256 + threadIdx.x;
  if (i >= G * HC) return;
  int g = i / HC;
  float cnt = (float)(gstart[g + 1] - gstart[g]);
  out[i] = sums[i] / fmaxf(cnt, 1.f);
}

static inline int cdiv(int64_t a, int b) { return (int)((a + b - 1) / b); }

extern "C" void kernel_launch(void* const* d_in, const int* in_sizes, int n_in,
                              void* d_out, int out_size, void* d_ws, size_t ws_size,
                              hipStream_t stream) {
  const float* x      = (const float*)d_in[0];
  const int*   eidx   = (const int*)d_in[1];
  const int*   batch  = (const int*)d_in[2];
  const float* lin0_w = (const float*)d_in[3];
  const float* lin0_b = (const float*)d_in[4];
  const float* W[3]  = {(const float*)d_in[5],  (const float*)d_in[9],  (const float*)d_in[13]};
  const float* As[3] = {(const float*)d_in[6],  (const float*)d_in[10], (const float*)d_in[14]};
  const float* Ad[3] = {(const float*)d_in[7],  (const float*)d_in[11], (const float*)d_in[15]};
  const float* Bi[3] = {(const float*)d_in[8],  (const float*)d_in[12], (const float*)d_in[16]};

  const int N = in_sizes[2];
  const int E = in_sizes[1] / 2;
  const int G = out_size / HC;
  const int* src = eidx;
  const int* dst = eidx + E;

  // ---- workspace layout (f16 buffers first, all 16B-aligned sizes) ----
  char* p = (char*)d_ws;
  f16* act0 = (f16*)p;  p += (size_t)N * A0P * 2;       // lin0 out, pitch 64
  f16* actv = (f16*)p;  p += (size_t)N * AP * 2;        // layer act, pitch 192
  f16* h16  = (f16*)p;  p += (size_t)N * HC * 2;        // GEMM out, pitch 168
  f16* Wf1  = (f16*)p;  p += (size_t)11 * 2 * 64 * 8 * 2;
  f16* Wf2  = (f16*)p;  p += (size_t)11 * 6 * 64 * 8 * 2;
  f16* Wf3  = (f16*)p;  p += (size_t)11 * 6 * 64 * 8 * 2;
  float* as_  = (float*)p; p += (size_t)N * NH * 4;
  float* ad_  = (float*)p; p += (size_t)N * NH * 4;
  float* sums = (float*)p; p += (size_t)G * HC * 4;
  int* gstart     = (int*)p; p += (size_t)(G + 1) * 4;
  int* row_ptr    = (int*)p; p += (size_t)(N + 1) * 4;
  int* cursor     = (int*)p; p += (size_t)N * 4;
  int* blksum     = (int*)p; p += 256 * 4;
  int* src_sorted = (int*)p; p += (size_t)E * 4;
  (void)ws_size;

  const __half2* H2 = (const __half2*)h16;
  const int nblk = cdiv(N, 1024);
  const int mfma_blocks = cdiv(cdiv(N, 16), 4);

  // ---- lin0 + elu -> fp16 act0 (pitch 64, zero-padded) ----
  gemm0_kernel<<<dim3(cdiv(N, 128), cdiv(A0P, 64)), 256, 0, stream>>>(
      x, lin0_w, lin0_b, act0, N, CC, CC, A0P);

  // ---- W fragment tables ----
  wconv_kernel<<<cdiv(11 * 2 * 64, 256), 256, 0, stream>>>(W[0], Wf1, CC, 2);
  wconv_kernel<<<cdiv(11 * 6 * 64, 256), 256, 0, stream>>>(W[1], Wf2, HC, 6);
  wconv_kernel<<<cdiv(11 * 6 * 64, 256), 256, 0, stream>>>(W[2], Wf3, HC, 6);

  // ---- build dst-sorted CSR (once) ----
  zero_i_kernel<<<cdiv(N, 256), 256, 0, stream>>>(cursor, N);
  hist_kernel<<<cdiv(E, 256), 256, 0, stream>>>(dst, cursor, E);
  scan1_kernel<<<nblk, 256, 0, stream>>>(cursor, row_ptr + 1, blksum, N);
  scan2_kernel<<<1, 256, 0, stream>>>(blksum, nblk);
  scan3_kernel<<<cdiv(N, 256), 256, 0, stream>>>(blksum, row_ptr + 1, row_ptr, cursor, N);
  scatter_kernel<<<cdiv(E, 256), 256, 0, stream>>>(src, dst, cursor, src_sorted, E);

  // ---- graph boundaries ----
  gbound_kernel<<<cdiv(N + 1, 256), 256, 0, stream>>>(batch, gstart, N, G);

  // ---- 3 GAT layers ----
  for (int l = 0; l < 3; ++l) {
    if (l == 0) {
      mfma_gemm_kernel<2><<<mfma_blocks, 256, 0, stream>>>(act0, Wf1, h16, N);
    } else {
      mfma_gemm_kernel<6><<<mfma_blocks, 256, 0, stream>>>(actv, (l == 1) ? Wf2 : Wf3, h16, N);
    }
    alpha_kernel<<<cdiv((int64_t)N * NH, 256), 256, 0, stream>>>(
        (const __half2*)h16, As[l], Ad[l], as_, ad_, N);
    gat_agg_kernel<<<cdiv(N, 4), 256, 0, stream>>>(
        row_ptr, src_sorted, H2, (const float4*)as_, (const float4*)ad_, Bi[l],
        (__half*)actv, N);
  }

  // ---- mean pool per graph ----
  zero_f_kernel<<<cdiv(G * HC, 256), 256, 0, stream>>>(sums, G * HC);
  pool2_kernel<<<dim3(G, PSPLIT), 192, 0, stream>>>((const __half*)actv, gstart, sums, G);
  out2_kernel<<<cdiv(G * HC, 256), 256, 0, stream>>>(sums, gstart, (float*)d_out, G);
}